// Round 3
// baseline (1067.610 us; speedup 1.0000x reference)
//
#include <hip/hip_runtime.h>
#include <math.h>

constexpr int LI = 8192;   // I (intermediate)
constexpr int LD = 2048;   // D (hidden)
constexpr int LN = 2048;   // N (tokens)
constexpr int LK = 32;     // top_k

// ---------------- Kernel 1: g = silu(x_chunk @ gate[l].T)  (fp32 vector GEMM)
// Tiles: 128(N) x 128(I) x 16(D), 256 threads, 8x8 micro-tile.
__global__ __launch_bounds__(256) void k_gate_gemm(
    const float* __restrict__ x, const float* __restrict__ gate,
    const int* __restrict__ layer_idx, float* __restrict__ g_full)
{
    const float* __restrict__ gw = gate + (size_t)layer_idx[0] * LI * LD;
    __shared__ float As[16][132];   // [k][n]
    __shared__ float Bs[16][132];   // [k][i]
    const int bi = blockIdx.x * 128;   // I block
    const int bn = blockIdx.y * 128;   // chunk-local N block
    const int tid = threadIdx.x;
    const int tx = tid & 15, ty = tid >> 4;
    float acc[8][8];
    #pragma unroll
    for (int m = 0; m < 8; ++m)
        #pragma unroll
        for (int n = 0; n < 8; ++n) acc[m][n] = 0.f;

    for (int k0 = 0; k0 < LD; k0 += 16) {
        #pragma unroll
        for (int v = 0; v < 2; ++v) {
            int li  = tid + v * 256;      // float4 slot 0..511
            int row = li >> 2;
            int kv  = (li & 3) << 2;
            float4 a = *(const float4*)(x  + (size_t)(bn + row) * LD + k0 + kv);
            As[kv + 0][row] = a.x; As[kv + 1][row] = a.y;
            As[kv + 2][row] = a.z; As[kv + 3][row] = a.w;
            float4 b = *(const float4*)(gw + (size_t)(bi + row) * LD + k0 + kv);
            Bs[kv + 0][row] = b.x; Bs[kv + 1][row] = b.y;
            Bs[kv + 2][row] = b.z; Bs[kv + 3][row] = b.w;
        }
        __syncthreads();
        #pragma unroll
        for (int kk = 0; kk < 16; ++kk) {
            float a[8], b[8];
            *(float4*)&a[0] = *(const float4*)&As[kk][ty * 8];
            *(float4*)&a[4] = *(const float4*)&As[kk][ty * 8 + 4];
            *(float4*)&b[0] = *(const float4*)&Bs[kk][tx * 8];
            *(float4*)&b[4] = *(const float4*)&Bs[kk][tx * 8 + 4];
            #pragma unroll
            for (int m = 0; m < 8; ++m)
                #pragma unroll
                for (int n = 0; n < 8; ++n)
                    acc[m][n] = fmaf(a[m], b[n], acc[m][n]);
        }
        __syncthreads();
    }
    #pragma unroll
    for (int m = 0; m < 8; ++m) {
        int row = bn + ty * 8 + m;
        #pragma unroll
        for (int n = 0; n < 8; n += 4) {
            float v0 = acc[m][n+0], v1 = acc[m][n+1], v2 = acc[m][n+2], v3 = acc[m][n+3];
            float4 o;
            o.x = v0 / (1.f + expf(-v0));
            o.y = v1 / (1.f + expf(-v1));
            o.z = v2 / (1.f + expf(-v2));
            o.w = v3 / (1.f + expf(-v3));
            *(float4*)(g_full + (size_t)row * LI + bi + tx * 8 + n) = o;
        }
    }
}

// ---------------- Kernel 2: exact top-K per row by |g| (radix select on float bits)
__global__ __launch_bounds__(256) void k_topk(
    const float* __restrict__ g_full, int* __restrict__ idx_out,
    float* __restrict__ gsel_out)
{
    __shared__ unsigned keys[LI];   // 32 KiB
    __shared__ int red[4];
    __shared__ int sel[LK];
    __shared__ int base_s;

    const int row  = blockIdx.x;
    const int tid  = threadIdx.x;
    const int lane = tid & 63, wid = tid >> 6;
    const float* __restrict__ g = g_full + (size_t)row * LI;

    if (tid < LK) sel[tid] = tid;   // belt: any coverage hole still yields a valid index
    for (int i = tid; i < LI; i += 256)
        keys[i] = __float_as_uint(fabsf(g[i]));   // positive floats: uint order == float order
    __syncthreads();

    // MSB->LSB radix select: prefix ends as the K-th largest key value.
    unsigned prefix = 0;
    int need = LK;
    for (int b = 31; b >= 0; --b) {
        unsigned candHi = (prefix >> b) | 1u;
        int c = 0;
        for (int i = tid; i < LI; i += 256)
            c += ((keys[i] >> b) == candHi);
        #pragma unroll
        for (int o = 32; o; o >>= 1) c += __shfl_down(c, o);
        if (lane == 0) red[wid] = c;
        __syncthreads();
        int total = red[0] + red[1] + red[2] + red[3];
        if (total >= need) prefix |= (1u << b);
        else               need  -= total;
        __syncthreads();
    }

    // Pass 1: ordered collect indices with key > kth (count <= K-1 when select is exact).
    if (tid == 0) base_s = 0;
    __syncthreads();
    for (int c0 = 0; c0 < LI; c0 += 256) {
        bool f = keys[c0 + tid] > prefix;
        unsigned long long m = __ballot(f);
        if (lane == 0) red[wid] = __popcll(m);
        __syncthreads();
        int wbase = base_s;
        for (int w = 0; w < wid; ++w) wbase += red[w];
        int pos = wbase + __popcll(m & ((1ull << lane) - 1ull));
        if (f && pos < LK) sel[pos] = c0 + tid;
        __syncthreads();
        if (tid == 0) base_s += red[0] + red[1] + red[2] + red[3];
        __syncthreads();
    }
    int cgt = base_s;            // uniform: read right after the trailing barrier
    if (cgt > LK) cgt = LK;
    int needt = LK - cgt;
    __syncthreads();             // FIX: everyone reads cgt before tid0 resets base_s
    if (tid == 0) base_s = 0;
    __syncthreads();

    // Pass 2: ties at == kth, lowest indices first (matches jax tie-break set-wise).
    // Fixed trip count, uniform barriers (no break).
    for (int c0 = 0; c0 < LI; c0 += 256) {
        bool f = keys[c0 + tid] == prefix;
        unsigned long long m = __ballot(f);
        if (lane == 0) red[wid] = __popcll(m);
        __syncthreads();
        int wbase = base_s;
        for (int w = 0; w < wid; ++w) wbase += red[w];
        int pos = wbase + __popcll(m & ((1ull << lane) - 1ull));
        if (f && pos < needt) sel[cgt + pos] = c0 + tid;
        __syncthreads();
        if (tid == 0) base_s += red[0] + red[1] + red[2] + red[3];
        __syncthreads();
    }

    if (tid < LK) {
        int j = sel[tid] & (LI - 1);   // clamp: gather stays in-bounds no matter what
        idx_out[row * LK + tid]  = j;
        gsel_out[row * LK + tid] = g[j];
    }
}

// ---------------- Kernel 3: u_sel = dot(up[idx], x[n]);  gu = g_sel * u_sel
__global__ __launch_bounds__(256) void k_up(
    const float* __restrict__ x, const float* __restrict__ up,
    const int* __restrict__ layer_idx, const int* __restrict__ idx,
    const float* __restrict__ gsel, float* __restrict__ gu)
{
    const float* __restrict__ uw = up + (size_t)layer_idx[0] * LI * LD;
    __shared__ float xs[LD];   // 8 KiB
    const int row  = blockIdx.x;
    const int tid  = threadIdx.x;
    const int lane = tid & 63, wid = tid >> 6;
    const float* __restrict__ xr = x + (size_t)row * LD;
    for (int i = tid * 4; i < LD; i += 1024)
        *(float4*)&xs[i] = *(const float4*)(xr + i);
    __syncthreads();
    for (int k = wid; k < LK; k += 4) {
        int j = idx[row * LK + k] & (LI - 1);   // clamped gather
        const float* __restrict__ ur = uw + (size_t)j * LD;
        float s = 0.f;
        for (int i = lane * 4; i < LD; i += 256) {
            float4 u4 = *(const float4*)(ur + i);
            s = fmaf(u4.x, xs[i + 0], s);
            s = fmaf(u4.y, xs[i + 1], s);
            s = fmaf(u4.z, xs[i + 2], s);
            s = fmaf(u4.w, xs[i + 3], s);
        }
        #pragma unroll
        for (int o = 32; o; o >>= 1) s += __shfl_down(s, o);
        if (lane == 0) gu[row * LK + k] = gsel[row * LK + k] * s;
    }
}

// ---------------- Kernel 4: transpose chunk down[D, i0:i0+ci] -> dT[ci, D]
__global__ __launch_bounds__(256) void k_transpose(
    const float* __restrict__ down, const int* __restrict__ layer_idx,
    int i0, float* __restrict__ dT)
{
    const float* __restrict__ dw = down + (size_t)layer_idx[0] * LD * LI;
    __shared__ float t[32][33];
    const int bi = blockIdx.x * 32;   // chunk-local I
    const int bd = blockIdx.y * 32;   // D
    const int tx = threadIdx.x & 31, ty = threadIdx.x >> 5;   // 32 x 8
    #pragma unroll
    for (int r = ty; r < 32; r += 8)
        t[r][tx] = dw[(size_t)(bd + r) * LI + i0 + bi + tx];
    __syncthreads();
    #pragma unroll
    for (int r = ty; r < 32; r += 8)
        dT[(size_t)(bi + r) * LD + bd + tx] = t[tx][r];
}

// ---------------- Kernel 5: out[n,:] (+)= sum_{k: idx in chunk} gu[n,k] * dT[idx-i0, :]
__global__ __launch_bounds__(256) void k_down(
    const float* __restrict__ dT, int i0, int ci,
    const int* __restrict__ idx, const float* __restrict__ gu,
    float* __restrict__ out, int accumulate)
{
    __shared__ int   js[LK];
    __shared__ float wgt[LK];
    const int row = blockIdx.x;
    const int tid = threadIdx.x;
    if (tid < LK) {
        js[tid]  = idx[row * LK + tid] & (LI - 1);   // clamped gather
        wgt[tid] = gu[row * LK + tid];
    }
    __syncthreads();
    float4 a0 = {0.f,0.f,0.f,0.f}, a1 = {0.f,0.f,0.f,0.f};
    for (int k = 0; k < LK; ++k) {
        int j = js[k] - i0;                       // uniform across block
        if ((unsigned)j < (unsigned)ci) {
            const float* __restrict__ dr = dT + (size_t)j * LD;
            float w = wgt[k];
            float4 v0 = *(const float4*)(dr + tid * 4);
            float4 v1 = *(const float4*)(dr + 1024 + tid * 4);
            a0.x = fmaf(w, v0.x, a0.x); a0.y = fmaf(w, v0.y, a0.y);
            a0.z = fmaf(w, v0.z, a0.z); a0.w = fmaf(w, v0.w, a0.w);
            a1.x = fmaf(w, v1.x, a1.x); a1.y = fmaf(w, v1.y, a1.y);
            a1.z = fmaf(w, v1.z, a1.z); a1.w = fmaf(w, v1.w, a1.w);
        }
    }
    float* o = out + (size_t)row * LD;
    if (accumulate) {
        float4 p0 = *(const float4*)(o + tid * 4);
        float4 p1 = *(const float4*)(o + 1024 + tid * 4);
        a0.x += p0.x; a0.y += p0.y; a0.z += p0.z; a0.w += p0.w;
        a1.x += p1.x; a1.y += p1.y; a1.z += p1.z; a1.w += p1.w;
    }
    *(float4*)(o + tid * 4) = a0;
    *(float4*)(o + 1024 + tid * 4) = a1;
}

extern "C" void kernel_launch(void* const* d_in, const int* in_sizes, int n_in,
                              void* d_out, int out_size, void* d_ws, size_t ws_size,
                              hipStream_t stream)
{
    const float* x      = (const float*)d_in[0];
    const float* gate   = (const float*)d_in[1];
    const float* up     = (const float*)d_in[2];
    const float* down   = (const float*)d_in[3];
    const int* layer_idx = (const int*)d_in[4];
    float* out = (float*)d_out;

    // ws layout: [idx | gsel | gu | big buffer (g chunks, then dT chunks)]
    const size_t NK = (size_t)LN * LK;
    int*   idx  = (int*)d_ws;
    float* gsel = (float*)((char*)d_ws + NK * 4);
    float* gu   = (float*)((char*)d_ws + 2 * NK * 4);
    const size_t META = ((3 * NK * 4) + 255) & ~(size_t)255;   // 768 KB
    if (ws_size <= META) return;                               // diagnostic: ws far too small
    char*  big  = (char*)d_ws + META;
    size_t avail = ws_size - META;

    // Token-chunk size for the g buffer (multiple of 128), I-chunk for dT (multiple of 32).
    size_t nc_max = avail / ((size_t)LI * 4);
    size_t ci_max = avail / ((size_t)LD * 4);
    int NC = (int)(nc_max > (size_t)LN ? (size_t)LN : nc_max) & ~127;
    int CI = (int)(ci_max > (size_t)LI ? (size_t)LI : ci_max) & ~31;
    if (NC < 128 || CI < 32) return;   // diagnostic: ws too small for any chunk

    float* gbuf = (float*)big;
    for (int n0 = 0; n0 < LN; n0 += NC) {
        int nc = (LN - n0 < NC) ? (LN - n0) : NC;
        k_gate_gemm<<<dim3(LI / 128, nc / 128), 256, 0, stream>>>(
            x + (size_t)n0 * LD, gate, layer_idx, gbuf);
        k_topk<<<nc, 256, 0, stream>>>(gbuf, idx + (size_t)n0 * LK, gsel + (size_t)n0 * LK);
        k_up<<<nc, 256, 0, stream>>>(x + (size_t)n0 * LD, up, layer_idx,
                                     idx + (size_t)n0 * LK, gsel + (size_t)n0 * LK,
                                     gu + (size_t)n0 * LK);
    }

    float* dTc = (float*)big;   // reuses the g region (all top-k done by now)
    int first = 1;
    for (int i0 = 0; i0 < LI; i0 += CI) {
        int ci = (LI - i0 < CI) ? (LI - i0) : CI;
        k_transpose<<<dim3(ci / 32, LD / 32), 256, 0, stream>>>(down, layer_idx, i0, dTc);
        k_down<<<LN, 256, 0, stream>>>(dTc, i0, ci, idx, gu, out, first ? 0 : 1);
        first = 0;
    }
}

// Round 4
// 585.145 us; speedup vs baseline: 1.8245x; 1.8245x over previous
//
#include <hip/hip_runtime.h>
#include <math.h>

constexpr int LI = 8192;   // I (intermediate)
constexpr int LD = 2048;   // D (hidden)
constexpr int LN = 2048;   // N (tokens)
constexpr int LK = 32;     // top_k

typedef short short8 __attribute__((ext_vector_type(8)));
typedef float f32x4 __attribute__((ext_vector_type(4)));
typedef const __attribute__((address_space(1))) void* gas1_t;
typedef __attribute__((address_space(3))) void* las3_t;

__device__ __forceinline__ void gload16(const void* g, void* l) {
    __builtin_amdgcn_global_load_lds((gas1_t)g, (las3_t)l, 16, 0, 0);
}

// ============================================================================
//                               NEW MFMA PATH
// ============================================================================

// ---- split fp32 -> bf16 hi + lo (RNE both), layer-indirected source
__global__ __launch_bounds__(256) void k_cvt(
    const float* __restrict__ src, const int* __restrict__ layer_idx,
    size_t lstride, unsigned short* __restrict__ hi,
    unsigned short* __restrict__ lo, int n4)
{
    const float* __restrict__ s = src + (size_t)layer_idx[0] * lstride;
    int i = blockIdx.x * 256 + threadIdx.x;
    int stride = gridDim.x * 256;
    for (; i < n4; i += stride) {
        float4 v = ((const float4*)s)[i];
        float f[4] = {v.x, v.y, v.z, v.w};
        unsigned short hh[4], ll[4];
        #pragma unroll
        for (int j = 0; j < 4; ++j) {
            unsigned u = __float_as_uint(f[j]);
            unsigned hb = (u + 0x7fffu + ((u >> 16) & 1u)) >> 16;
            float r = f[j] - __uint_as_float(hb << 16);
            unsigned u2 = __float_as_uint(r);
            unsigned lb = (u2 + 0x7fffu + ((u2 >> 16) & 1u)) >> 16;
            hh[j] = (unsigned short)hb; ll[j] = (unsigned short)lb;
        }
        ushort4 h = {hh[0], hh[1], hh[2], hh[3]};
        ushort4 l = {ll[0], ll[1], ll[2], ll[3]};
        ((ushort4*)hi)[i] = h;
        ((ushort4*)lo)[i] = l;
    }
}

// ---- Z = x @ gw^T via bf16x3 MFMA (hi*hi + hi*lo + lo*hi), fp32 out.
// 128x128 tile, BK=64, 4 waves (2x2), each wave 64x64 out (4x4 frags 16x16x32).
// LDS tiles XOR-swizzled (chunk ^= row&7) via pre-swizzled global source.
__global__ __launch_bounds__(256) void k_gemm_z(
    const unsigned short* __restrict__ xh, const unsigned short* __restrict__ xl,
    const unsigned short* __restrict__ wh, const unsigned short* __restrict__ wl,
    int n0, float* __restrict__ z)
{
    __shared__ short lds[32768];   // Ah|Al|Bh|Bl, each [128][64] bf16 = 16KB
    short* Ah = lds;
    short* Al = lds + 8192;
    short* Bh = lds + 16384;
    short* Bl = lds + 24576;

    const int tid = threadIdx.x;
    const int w = tid >> 6, lane = tid & 63;
    const int bn = blockIdx.y * 128;   // token rows (chunk-local)
    const int bi = blockIdx.x * 128;   // neuron rows

    // staging: wave w fills rows [w*32, w*32+32) of each tile; per instr 8 rows.
    const int srow   = w * 32 + (lane >> 3);
    const int schunk = (lane & 7) ^ ((lane >> 3) & 7);   // inverse-swizzled source chunk
    const unsigned short* xbh = xh + (size_t)(n0 + bn + srow) * LD + schunk * 8;
    const unsigned short* xbl = xl + (size_t)(n0 + bn + srow) * LD + schunk * 8;
    const unsigned short* wbh = wh + (size_t)(bi + srow) * LD + schunk * 8;
    const unsigned short* wbl = wl + (size_t)(bi + srow) * LD + schunk * 8;

    f32x4 acc[4][4];
    #pragma unroll
    for (int m = 0; m < 4; ++m)
        #pragma unroll
        for (int n = 0; n < 4; ++n) acc[m][n] = (f32x4){0.f, 0.f, 0.f, 0.f};

    const int wm = (w >> 1) * 64, wn = (w & 1) * 64;

    #define STAGE(k0)                                                          \
        {                                                                      \
            _Pragma("unroll")                                                  \
            for (int t = 0; t < 4; ++t) {                                      \
                int ldo = (w * 32 + t * 8) * 64;                               \
                size_t go = (size_t)t * 8 * LD + (k0);                         \
                gload16(xbh + go, Ah + ldo);                                   \
                gload16(xbl + go, Al + ldo);                                   \
                gload16(wbh + go, Bh + ldo);                                   \
                gload16(wbl + go, Bl + ldo);                                   \
            }                                                                  \
        }

    STAGE(0);
    __syncthreads();
    for (int k0 = 0;;) {
        #pragma unroll
        for (int ks = 0; ks < 2; ++ks) {
            short8 a_h[4], a_l[4], b_h[4], b_l[4];
            #pragma unroll
            for (int m = 0; m < 4; ++m) {
                int lr = wm + m * 16 + (lane & 15);
                int lc = ks * 4 + (lane >> 4);
                int off = lr * 64 + ((lc ^ (lr & 7)) << 3);
                a_h[m] = *(const short8*)(Ah + off);
                a_l[m] = *(const short8*)(Al + off);
            }
            #pragma unroll
            for (int n = 0; n < 4; ++n) {
                int lr = wn + n * 16 + (lane & 15);
                int lc = ks * 4 + (lane >> 4);
                int off = lr * 64 + ((lc ^ (lr & 7)) << 3);
                b_h[n] = *(const short8*)(Bh + off);
                b_l[n] = *(const short8*)(Bl + off);
            }
            #pragma unroll
            for (int m = 0; m < 4; ++m)
                #pragma unroll
                for (int n = 0; n < 4; ++n) {
                    acc[m][n] = __builtin_amdgcn_mfma_f32_16x16x32_bf16(a_h[m], b_h[n], acc[m][n], 0, 0, 0);
                    acc[m][n] = __builtin_amdgcn_mfma_f32_16x16x32_bf16(a_h[m], b_l[n], acc[m][n], 0, 0, 0);
                    acc[m][n] = __builtin_amdgcn_mfma_f32_16x16x32_bf16(a_l[m], b_h[n], acc[m][n], 0, 0, 0);
                }
        }
        k0 += 64;
        if (k0 >= LD) break;
        __syncthreads();   // all waves done reading LDS
        STAGE(k0);
        __syncthreads();   // staging complete (compiler drains vmcnt)
    }

    // epilogue: C/D frag layout col=lane&15, row=(lane>>4)*4+reg  [m89/m91]
    #pragma unroll
    for (int m = 0; m < 4; ++m) {
        int rb = bn + wm + m * 16 + (lane >> 4) * 4;
        #pragma unroll
        for (int n = 0; n < 4; ++n) {
            int cb = bi + wn + n * 16 + (lane & 15);
            #pragma unroll
            for (int r = 0; r < 4; ++r)
                z[(size_t)(rb + r) * LI + cb] = acc[m][n][r];
        }
    }
    #undef STAGE
}

// ---- exact top-K from approximate z: radix-select approx 32nd key, take band
// candidates, recompute their dots exactly in fp32, re-rank, fuse up-proj.
__global__ __launch_bounds__(256) void k_topk2(
    const float* __restrict__ z, const float* __restrict__ x,
    const float* __restrict__ gate, const float* __restrict__ up,
    const int* __restrict__ layer_idx, int n0,
    int* __restrict__ idx_out, float* __restrict__ gu_out)
{
    __shared__ unsigned keys[LI];   // 32KB
    __shared__ float xs[LD];        // 8KB
    __shared__ int red[4];
    __shared__ int base_s;
    __shared__ int cand[128];
    __shared__ float cz[128];       // exact silu(z) per candidate
    __shared__ float ckey[128];     // exact |silu(z)|
    __shared__ int seli[LK];
    __shared__ float selg[LK];

    const int row = blockIdx.x;        // chunk-local
    const int grow = n0 + row;
    const int tid = threadIdx.x;
    const int lane = tid & 63, w = tid >> 6;
    const float* __restrict__ zr = z + (size_t)row * LI;
    const float* __restrict__ xr = x + (size_t)grow * LD;
    const float* __restrict__ gw = gate + (size_t)layer_idx[0] * LI * LD;
    const float* __restrict__ uw = up + (size_t)layer_idx[0] * LI * LD;

    for (int i = tid * 4; i < LD; i += 1024)
        *(float4*)&xs[i] = *(const float4*)(xr + i);
    for (int i = tid; i < LI; i += 256) {
        float zv = zr[i];
        float g = zv / (1.f + expf(-zv));
        keys[i] = __float_as_uint(fabsf(g));
    }
    __syncthreads();

    // radix select (exact on the approximate keys): prefix = 32nd largest
    unsigned prefix = 0; int need = LK;
    for (int b = 31; b >= 0; --b) {
        unsigned candHi = (prefix >> b) | 1u;
        int c = 0;
        for (int i = tid; i < LI; i += 256)
            c += ((keys[i] >> b) == candHi);
        #pragma unroll
        for (int o = 32; o; o >>= 1) c += __shfl_down(c, o);
        if (lane == 0) red[w] = c;
        __syncthreads();
        int total = red[0] + red[1] + red[2] + red[3];
        if (total >= need) prefix |= (1u << b);
        else               need  -= total;
        __syncthreads();
    }
    const float bandlo = __uint_as_float(prefix) - 2e-3f;   // >> bf16x3 error bound

    // ordered candidate collection (ascending index), cap 128
    if (tid == 0) base_s = 0;
    __syncthreads();
    for (int c0 = 0; c0 < LI; c0 += 256) {
        bool f = __uint_as_float(keys[c0 + tid]) >= bandlo;
        unsigned long long m = __ballot(f);
        if (lane == 0) red[w] = __popcll(m);
        __syncthreads();
        int wbase = base_s;
        for (int ww = 0; ww < w; ++ww) wbase += red[ww];
        int pos = wbase + __popcll(m & ((1ull << lane) - 1ull));
        if (f && pos < 128) cand[pos] = c0 + tid;
        __syncthreads();
        if (tid == 0) base_s += red[0] + red[1] + red[2] + red[3];
        __syncthreads();
    }
    const int count = base_s < 128 ? base_s : 128;

    // exact fp32 recompute of candidate dots (wave per candidate)
    for (int c = w; c < count; c += 4) {
        int j = cand[c] & (LI - 1);
        const float* __restrict__ gr = gw + (size_t)j * LD;
        float s = 0.f;
        for (int i = lane * 4; i < LD; i += 256) {
            float4 g4 = *(const float4*)(gr + i);
            s = fmaf(g4.x, xs[i + 0], s); s = fmaf(g4.y, xs[i + 1], s);
            s = fmaf(g4.z, xs[i + 2], s); s = fmaf(g4.w, xs[i + 3], s);
        }
        #pragma unroll
        for (int o = 32; o; o >>= 1) s += __shfl_down(s, o);
        if (lane == 0) {
            float g = s / (1.f + expf(-s));
            cz[c] = g;
            ckey[c] = fabsf(g);
        }
    }
    __syncthreads();

    // top-32 among candidates by (exact key desc, index asc) — wave 0
    if (w == 0) {
        float k1 = lane      < count ? ckey[lane]      : -1.f;
        float k2 = lane + 64 < count ? ckey[lane + 64] : -1.f;
        int   i1 = lane      < count ? cand[lane]      : 0x7fffffff;
        int   i2 = lane + 64 < count ? cand[lane + 64] : 0x7fffffff;
        int   p1 = lane, p2 = lane + 64;
        for (int slot = 0; slot < LK; ++slot) {
            float bk; int bidx, bp;
            if (k1 > k2 || (k1 == k2 && i1 < i2)) { bk = k1; bidx = i1; bp = p1; }
            else                                  { bk = k2; bidx = i2; bp = p2; }
            #pragma unroll
            for (int o = 1; o < 64; o <<= 1) {
                float ok = __shfl_xor(bk, o);
                int  oi = __shfl_xor(bidx, o);
                int  op = __shfl_xor(bp, o);
                if (ok > bk || (ok == bk && oi < bidx)) { bk = ok; bidx = oi; bp = op; }
            }
            if (lane == 0) { seli[slot] = bidx; selg[slot] = cz[bp & 127]; }
            if (p1 == bp) k1 = -1.f;
            if (p2 == bp) k2 = -1.f;
        }
    }
    __syncthreads();

    // fused up-proj: gu = silu_exact * dot(up[sel], x)
    for (int k = w; k < LK; k += 4) {
        int j = seli[k] & (LI - 1);
        const float* __restrict__ ur = uw + (size_t)j * LD;
        float s = 0.f;
        for (int i = lane * 4; i < LD; i += 256) {
            float4 u4 = *(const float4*)(ur + i);
            s = fmaf(u4.x, xs[i + 0], s); s = fmaf(u4.y, xs[i + 1], s);
            s = fmaf(u4.z, xs[i + 2], s); s = fmaf(u4.w, xs[i + 3], s);
        }
        #pragma unroll
        for (int o = 32; o; o >>= 1) s += __shfl_down(s, o);
        if (lane == 0) {
            idx_out[grow * LK + k] = seli[k];
            gu_out[grow * LK + k]  = selg[k] * s;
        }
    }
}

// ============================================================================
//                      FALLBACK fp32 PATH (round-3, passing)
// ============================================================================

__global__ __launch_bounds__(256) void k_gate_gemm(
    const float* __restrict__ x, const float* __restrict__ gate,
    const int* __restrict__ layer_idx, float* __restrict__ g_full)
{
    const float* __restrict__ gw = gate + (size_t)layer_idx[0] * LI * LD;
    __shared__ float As[16][132];
    __shared__ float Bs[16][132];
    const int bi = blockIdx.x * 128;
    const int bn = blockIdx.y * 128;
    const int tid = threadIdx.x;
    const int tx = tid & 15, ty = tid >> 4;
    float acc[8][8];
    #pragma unroll
    for (int m = 0; m < 8; ++m)
        #pragma unroll
        for (int n = 0; n < 8; ++n) acc[m][n] = 0.f;

    for (int k0 = 0; k0 < LD; k0 += 16) {
        #pragma unroll
        for (int v = 0; v < 2; ++v) {
            int li  = tid + v * 256;
            int row = li >> 2;
            int kv  = (li & 3) << 2;
            float4 a = *(const float4*)(x  + (size_t)(bn + row) * LD + k0 + kv);
            As[kv + 0][row] = a.x; As[kv + 1][row] = a.y;
            As[kv + 2][row] = a.z; As[kv + 3][row] = a.w;
            float4 b = *(const float4*)(gw + (size_t)(bi + row) * LD + k0 + kv);
            Bs[kv + 0][row] = b.x; Bs[kv + 1][row] = b.y;
            Bs[kv + 2][row] = b.z; Bs[kv + 3][row] = b.w;
        }
        __syncthreads();
        #pragma unroll
        for (int kk = 0; kk < 16; ++kk) {
            float a[8], b[8];
            *(float4*)&a[0] = *(const float4*)&As[kk][ty * 8];
            *(float4*)&a[4] = *(const float4*)&As[kk][ty * 8 + 4];
            *(float4*)&b[0] = *(const float4*)&Bs[kk][tx * 8];
            *(float4*)&b[4] = *(const float4*)&Bs[kk][tx * 8 + 4];
            #pragma unroll
            for (int m = 0; m < 8; ++m)
                #pragma unroll
                for (int n = 0; n < 8; ++n)
                    acc[m][n] = fmaf(a[m], b[n], acc[m][n]);
        }
        __syncthreads();
    }
    #pragma unroll
    for (int m = 0; m < 8; ++m) {
        int row = bn + ty * 8 + m;
        #pragma unroll
        for (int n = 0; n < 8; n += 4) {
            float v0 = acc[m][n+0], v1 = acc[m][n+1], v2 = acc[m][n+2], v3 = acc[m][n+3];
            float4 o;
            o.x = v0 / (1.f + expf(-v0));
            o.y = v1 / (1.f + expf(-v1));
            o.z = v2 / (1.f + expf(-v2));
            o.w = v3 / (1.f + expf(-v3));
            *(float4*)(g_full + (size_t)row * LI + bi + tx * 8 + n) = o;
        }
    }
}

__global__ __launch_bounds__(256) void k_topk(
    const float* __restrict__ g_full, int* __restrict__ idx_out,
    float* __restrict__ gsel_out)
{
    __shared__ unsigned keys[LI];
    __shared__ int red[4];
    __shared__ int sel[LK];
    __shared__ int base_s;

    const int row  = blockIdx.x;
    const int tid  = threadIdx.x;
    const int lane = tid & 63, wid = tid >> 6;
    const float* __restrict__ g = g_full + (size_t)row * LI;

    if (tid < LK) sel[tid] = tid;
    for (int i = tid; i < LI; i += 256)
        keys[i] = __float_as_uint(fabsf(g[i]));
    __syncthreads();

    unsigned prefix = 0;
    int need = LK;
    for (int b = 31; b >= 0; --b) {
        unsigned candHi = (prefix >> b) | 1u;
        int c = 0;
        for (int i = tid; i < LI; i += 256)
            c += ((keys[i] >> b) == candHi);
        #pragma unroll
        for (int o = 32; o; o >>= 1) c += __shfl_down(c, o);
        if (lane == 0) red[wid] = c;
        __syncthreads();
        int total = red[0] + red[1] + red[2] + red[3];
        if (total >= need) prefix |= (1u << b);
        else               need  -= total;
        __syncthreads();
    }

    if (tid == 0) base_s = 0;
    __syncthreads();
    for (int c0 = 0; c0 < LI; c0 += 256) {
        bool f = keys[c0 + tid] > prefix;
        unsigned long long m = __ballot(f);
        if (lane == 0) red[wid] = __popcll(m);
        __syncthreads();
        int wbase = base_s;
        for (int w = 0; w < wid; ++w) wbase += red[w];
        int pos = wbase + __popcll(m & ((1ull << lane) - 1ull));
        if (f && pos < LK) sel[pos] = c0 + tid;
        __syncthreads();
        if (tid == 0) base_s += red[0] + red[1] + red[2] + red[3];
        __syncthreads();
    }
    int cgt = base_s;
    if (cgt > LK) cgt = LK;
    int needt = LK - cgt;
    __syncthreads();
    if (tid == 0) base_s = 0;
    __syncthreads();

    for (int c0 = 0; c0 < LI; c0 += 256) {
        bool f = keys[c0 + tid] == prefix;
        unsigned long long m = __ballot(f);
        if (lane == 0) red[wid] = __popcll(m);
        __syncthreads();
        int wbase = base_s;
        for (int w = 0; w < wid; ++w) wbase += red[w];
        int pos = wbase + __popcll(m & ((1ull << lane) - 1ull));
        if (f && pos < needt) sel[cgt + pos] = c0 + tid;
        __syncthreads();
        if (tid == 0) base_s += red[0] + red[1] + red[2] + red[3];
        __syncthreads();
    }

    if (tid < LK) {
        int j = sel[tid] & (LI - 1);
        idx_out[row * LK + tid]  = j;
        gsel_out[row * LK + tid] = g[j];
    }
}

__global__ __launch_bounds__(256) void k_up(
    const float* __restrict__ x, const float* __restrict__ up,
    const int* __restrict__ layer_idx, const int* __restrict__ idx,
    const float* __restrict__ gsel, float* __restrict__ gu)
{
    const float* __restrict__ uw = up + (size_t)layer_idx[0] * LI * LD;
    __shared__ float xs[LD];
    const int row  = blockIdx.x;
    const int tid  = threadIdx.x;
    const int lane = tid & 63, wid = tid >> 6;
    const float* __restrict__ xr = x + (size_t)row * LD;
    for (int i = tid * 4; i < LD; i += 1024)
        *(float4*)&xs[i] = *(const float4*)(xr + i);
    __syncthreads();
    for (int k = wid; k < LK; k += 4) {
        int j = idx[row * LK + k] & (LI - 1);
        const float* __restrict__ ur = uw + (size_t)j * LD;
        float s = 0.f;
        for (int i = lane * 4; i < LD; i += 256) {
            float4 u4 = *(const float4*)(ur + i);
            s = fmaf(u4.x, xs[i + 0], s);
            s = fmaf(u4.y, xs[i + 1], s);
            s = fmaf(u4.z, xs[i + 2], s);
            s = fmaf(u4.w, xs[i + 3], s);
        }
        #pragma unroll
        for (int o = 32; o; o >>= 1) s += __shfl_down(s, o);
        if (lane == 0) gu[row * LK + k] = gsel[row * LK + k] * s;
    }
}

// ============================================================================
//                      SHARED TAIL (down projection)
// ============================================================================

__global__ __launch_bounds__(256) void k_transpose(
    const float* __restrict__ down, const int* __restrict__ layer_idx,
    int i0, float* __restrict__ dT)
{
    const float* __restrict__ dw = down + (size_t)layer_idx[0] * LD * LI;
    __shared__ float t[32][33];
    const int bi = blockIdx.x * 32;
    const int bd = blockIdx.y * 32;
    const int tx = threadIdx.x & 31, ty = threadIdx.x >> 5;
    #pragma unroll
    for (int r = ty; r < 32; r += 8)
        t[r][tx] = dw[(size_t)(bd + r) * LI + i0 + bi + tx];
    __syncthreads();
    #pragma unroll
    for (int r = ty; r < 32; r += 8)
        dT[(size_t)(bi + r) * LD + bd + tx] = t[tx][r];
}

__global__ __launch_bounds__(256) void k_down(
    const float* __restrict__ dT, int i0, int ci,
    const int* __restrict__ idx, const float* __restrict__ gu,
    float* __restrict__ out, int accumulate)
{
    __shared__ int   js[LK];
    __shared__ float wgt[LK];
    const int row = blockIdx.x;
    const int tid = threadIdx.x;
    if (tid < LK) {
        js[tid]  = idx[row * LK + tid] & (LI - 1);
        wgt[tid] = gu[row * LK + tid];
    }
    __syncthreads();
    float4 a0 = {0.f,0.f,0.f,0.f}, a1 = {0.f,0.f,0.f,0.f};
    for (int k = 0; k < LK; ++k) {
        int j = js[k] - i0;
        if ((unsigned)j < (unsigned)ci) {
            const float* __restrict__ dr = dT + (size_t)j * LD;
            float w = wgt[k];
            float4 v0 = *(const float4*)(dr + tid * 4);
            float4 v1 = *(const float4*)(dr + 1024 + tid * 4);
            a0.x = fmaf(w, v0.x, a0.x); a0.y = fmaf(w, v0.y, a0.y);
            a0.z = fmaf(w, v0.z, a0.z); a0.w = fmaf(w, v0.w, a0.w);
            a1.x = fmaf(w, v1.x, a1.x); a1.y = fmaf(w, v1.y, a1.y);
            a1.z = fmaf(w, v1.z, a1.z); a1.w = fmaf(w, v1.w, a1.w);
        }
    }
    float* o = out + (size_t)row * LD;
    if (accumulate) {
        float4 p0 = *(const float4*)(o + tid * 4);
        float4 p1 = *(const float4*)(o + 1024 + tid * 4);
        a0.x += p0.x; a0.y += p0.y; a0.z += p0.z; a0.w += p0.w;
        a1.x += p1.x; a1.y += p1.y; a1.z += p1.z; a1.w += p1.w;
    }
    *(float4*)(o + tid * 4) = a0;
    *(float4*)(o + 1024 + tid * 4) = a1;
}

// ============================================================================

extern "C" void kernel_launch(void* const* d_in, const int* in_sizes, int n_in,
                              void* d_out, int out_size, void* d_ws, size_t ws_size,
                              hipStream_t stream)
{
    const float* x      = (const float*)d_in[0];
    const float* gate   = (const float*)d_in[1];
    const float* up     = (const float*)d_in[2];
    const float* down   = (const float*)d_in[3];
    const int* layer_idx = (const int*)d_in[4];
    float* out = (float*)d_out;

    const size_t NK = (size_t)LN * LK;
    int*   idx  = (int*)d_ws;
    float* gsel = (float*)((char*)d_ws + NK * 4);
    float* gu   = (float*)((char*)d_ws + 2 * NK * 4);
    const size_t META = ((3 * NK * 4) + 255) & ~(size_t)255;
    if (ws_size <= META) return;
    char* base = (char*)d_ws + META;

    const size_t xcnt = (size_t)LN * LD;
    const size_t wcnt = (size_t)LI * LD;
    const size_t fixed = META + (2 * xcnt + 2 * wcnt) * 2;   // bf16 hi/lo buffers

    if (ws_size >= fixed + (size_t)128 * LI * 4) {
        // ---------------- MFMA path ----------------
        unsigned short* xhp = (unsigned short*)base;
        unsigned short* xlp = xhp + xcnt;
        unsigned short* whp = xlp + xcnt;
        unsigned short* wlp = whp + wcnt;
        float* big = (float*)(wlp + wcnt);
        size_t avail = ws_size - fixed;

        size_t nc_max = avail / ((size_t)LI * 4);
        size_t ci_max = avail / ((size_t)LD * 4);
        int NC = (int)(nc_max > (size_t)LN ? (size_t)LN : nc_max) & ~127;
        int CI = (int)(ci_max > (size_t)LI ? (size_t)LI : ci_max) & ~31;

        k_cvt<<<1024, 256, 0, stream>>>(x, layer_idx, 0, xhp, xlp, (int)(xcnt / 4));
        k_cvt<<<2048, 256, 0, stream>>>(gate, layer_idx, wcnt, whp, wlp, (int)(wcnt / 4));

        for (int n0 = 0; n0 < LN; n0 += NC) {
            int nc = (LN - n0 < NC) ? (LN - n0) : NC;
            k_gemm_z<<<dim3(LI / 128, nc / 128), 256, 0, stream>>>(
                xhp, xlp, whp, wlp, n0, big);
            k_topk2<<<nc, 256, 0, stream>>>(big, x, gate, up, layer_idx, n0, idx, gu);
        }

        int first = 1;
        for (int i0 = 0; i0 < LI; i0 += CI) {
            int ci = (LI - i0 < CI) ? (LI - i0) : CI;
            k_transpose<<<dim3(ci / 32, LD / 32), 256, 0, stream>>>(down, layer_idx, i0, big);
            k_down<<<LN, 256, 0, stream>>>(big, i0, ci, idx, gu, out, first ? 0 : 1);
            first = 0;
        }
    } else {
        // ---------------- fallback fp32 path (round-3, passing) ----------------
        size_t avail = ws_size - META;
        size_t nc_max = avail / ((size_t)LI * 4);
        size_t ci_max = avail / ((size_t)LD * 4);
        int NC = (int)(nc_max > (size_t)LN ? (size_t)LN : nc_max) & ~127;
        int CI = (int)(ci_max > (size_t)LI ? (size_t)LI : ci_max) & ~31;
        if (NC < 128 || CI < 32) return;
        float* gbuf = (float*)base;

        for (int n0 = 0; n0 < LN; n0 += NC) {
            int nc = (LN - n0 < NC) ? (LN - n0) : NC;
            k_gate_gemm<<<dim3(LI / 128, nc / 128), 256, 0, stream>>>(
                x + (size_t)n0 * LD, gate, layer_idx, gbuf);
            k_topk<<<nc, 256, 0, stream>>>(gbuf, idx + (size_t)n0 * LK, gsel + (size_t)n0 * LK);
            k_up<<<nc, 256, 0, stream>>>(x + (size_t)n0 * LD, up, layer_idx,
                                         idx + (size_t)n0 * LK, gsel + (size_t)n0 * LK,
                                         gu + (size_t)n0 * LK);
        }
        int first = 1;
        for (int i0 = 0; i0 < LI; i0 += CI) {
            int ci = (LI - i0 < CI) ? (LI - i0) : CI;
            k_transpose<<<dim3(ci / 32, LD / 32), 256, 0, stream>>>(down, layer_idx, i0, (float*)base);
            k_down<<<LN, 256, 0, stream>>>((float*)base, i0, ci, idx, gu, out, first ? 0 : 1);
            first = 0;
        }
    }
}

// Round 5
// 433.183 us; speedup vs baseline: 2.4646x; 1.3508x over previous
//
#include <hip/hip_runtime.h>
#include <math.h>

constexpr int LI = 8192;   // I (intermediate)
constexpr int LD = 2048;   // D (hidden)
constexpr int LN = 2048;   // N (tokens)
constexpr int LK = 32;     // top_k
constexpr int CAP = 192;   // candidate band cap per row

typedef short short8 __attribute__((ext_vector_type(8)));
typedef float f32x4 __attribute__((ext_vector_type(4)));
typedef const __attribute__((address_space(1))) void* gas1_t;
typedef __attribute__((address_space(3))) void* las3_t;

__device__ __forceinline__ void gload16(const void* g, void* l) {
    __builtin_amdgcn_global_load_lds((gas1_t)g, (las3_t)l, 16, 0, 0);
}

// ---- fp32 -> bf16 (RNE), layer-indirected source
__global__ __launch_bounds__(256) void k_cvt_h(
    const float* __restrict__ src, const int* __restrict__ layer_idx,
    size_t lstride, unsigned short* __restrict__ hi, int n4)
{
    const float* __restrict__ s = src + (size_t)layer_idx[0] * lstride;
    int i = blockIdx.x * 256 + threadIdx.x;
    int stride = gridDim.x * 256;
    for (; i < n4; i += stride) {
        float4 v = ((const float4*)s)[i];
        float f[4] = {v.x, v.y, v.z, v.w};
        unsigned short hh[4];
        #pragma unroll
        for (int j = 0; j < 4; ++j) {
            unsigned u = __float_as_uint(f[j]);
            hh[j] = (unsigned short)((u + 0x7fffu + ((u >> 16) & 1u)) >> 16);
        }
        ushort4 h = {hh[0], hh[1], hh[2], hh[3]};
        ((ushort4*)hi)[i] = h;
    }
}

// ---- zk = bf16(|silu(x @ gw^T)|) via single bf16 MFMA, 128x128 tile, BK=64.
// Structure verified in round 4 (passed); lo-terms removed, key epilogue added.
__global__ __launch_bounds__(256) void k_gemm_z(
    const unsigned short* __restrict__ xh, const unsigned short* __restrict__ wh,
    unsigned short* __restrict__ zk)
{
    __shared__ short lds[16384];   // Ah|Bh, each [128][64] bf16 = 16KB
    short* Ah = lds;
    short* Bh = lds + 8192;

    const int tid = threadIdx.x;
    const int w = tid >> 6, lane = tid & 63;
    const int bn = blockIdx.y * 128;   // token rows
    const int bi = blockIdx.x * 128;   // neuron rows

    const int srow   = w * 32 + (lane >> 3);
    const int schunk = (lane & 7) ^ ((lane >> 3) & 7);   // inverse-swizzled source
    const unsigned short* xbh = xh + (size_t)(bn + srow) * LD + schunk * 8;
    const unsigned short* wbh = wh + (size_t)(bi + srow) * LD + schunk * 8;

    f32x4 acc[4][4];
    #pragma unroll
    for (int m = 0; m < 4; ++m)
        #pragma unroll
        for (int n = 0; n < 4; ++n) acc[m][n] = (f32x4){0.f, 0.f, 0.f, 0.f};

    const int wm = (w >> 1) * 64, wn = (w & 1) * 64;

    #define STAGE(k0)                                                          \
        {                                                                      \
            _Pragma("unroll")                                                  \
            for (int t = 0; t < 4; ++t) {                                      \
                int ldo = (w * 32 + t * 8) * 64;                               \
                size_t go = (size_t)t * 8 * LD + (k0);                         \
                gload16(xbh + go, Ah + ldo);                                   \
                gload16(wbh + go, Bh + ldo);                                   \
            }                                                                  \
        }

    STAGE(0);
    __syncthreads();
    for (int k0 = 0;;) {
        #pragma unroll
        for (int ks = 0; ks < 2; ++ks) {
            short8 a_h[4], b_h[4];
            #pragma unroll
            for (int m = 0; m < 4; ++m) {
                int lr = wm + m * 16 + (lane & 15);
                int lc = ks * 4 + (lane >> 4);
                a_h[m] = *(const short8*)(Ah + lr * 64 + ((lc ^ (lr & 7)) << 3));
            }
            #pragma unroll
            for (int n = 0; n < 4; ++n) {
                int lr = wn + n * 16 + (lane & 15);
                int lc = ks * 4 + (lane >> 4);
                b_h[n] = *(const short8*)(Bh + lr * 64 + ((lc ^ (lr & 7)) << 3));
            }
            #pragma unroll
            for (int m = 0; m < 4; ++m)
                #pragma unroll
                for (int n = 0; n < 4; ++n)
                    acc[m][n] = __builtin_amdgcn_mfma_f32_16x16x32_bf16(a_h[m], b_h[n], acc[m][n], 0, 0, 0);
        }
        k0 += 64;
        if (k0 >= LD) break;
        __syncthreads();
        STAGE(k0);
        __syncthreads();
    }

    // epilogue: key = bf16(|silu(z)|); C/D layout col=lane&15, row=(lane>>4)*4+r
    #pragma unroll
    for (int m = 0; m < 4; ++m) {
        int rb = bn + wm + m * 16 + (lane >> 4) * 4;
        #pragma unroll
        for (int n = 0; n < 4; ++n) {
            int cb = bi + wn + n * 16 + (lane & 15);
            #pragma unroll
            for (int r = 0; r < 4; ++r) {
                float zv = acc[m][n][r];
                float g = zv / (1.f + expf(-zv));
                unsigned u = __float_as_uint(fabsf(g));
                zk[(size_t)(rb + r) * LI + cb] =
                    (unsigned short)((u + 0x7fffu + ((u >> 16) & 1u)) >> 16);
            }
        }
    }
    #undef STAGE
}

// ---- per-row band selection: 4096-bin histogram on bf16 key bits, threshold
// bin covering rank-32, collect keys >= binfloor - MARGIN (superset of top-32).
__global__ __launch_bounds__(256) void k_select(
    const unsigned short* __restrict__ zk, int* __restrict__ band,
    int* __restrict__ bandcnt, int* __restrict__ ghist)
{
    __shared__ int hist[4096];   // 16 KB
    __shared__ int sums[256];
    __shared__ int red[4];
    __shared__ int base_s;
    __shared__ int thrbin_s;

    const int row = blockIdx.x;
    const int tid = threadIdx.x;
    const int lane = tid & 63, w = tid >> 6;
    const unsigned short* __restrict__ z = zk + (size_t)row * LI;

    if (tid == 0) thrbin_s = 0;
    for (int i = tid; i < 4096; i += 256) hist[i] = 0;
    __syncthreads();
    for (int i = tid; i < LI; i += 256)
        atomicAdd(&hist[z[i] >> 3], 1);   // sign=0: uint order == value order
    __syncthreads();

    int own = 0;
    #pragma unroll
    for (int b = 0; b < 16; ++b) own += hist[tid * 16 + b];
    sums[tid] = own;
    __syncthreads();
    // suffix inclusive scan: sums[t] = sum_{u>=t} own_u
    for (int st = 1; st < 256; st <<= 1) {
        int v = (tid + st < 256) ? sums[tid + st] : 0;
        __syncthreads();
        sums[tid] += v;
        __syncthreads();
    }
    int after = (tid < 255) ? sums[tid + 1] : 0;   // strictly above my 16 bins
    if (after < LK && after + own >= LK) {          // unique crossing thread
        int cum = after;
        for (int b = 15; b >= 0; --b) {
            cum += hist[tid * 16 + b];
            if (cum >= LK) { thrbin_s = tid * 16 + b; break; }
        }
    }
    __syncthreads();
    const float bandlo =
        __uint_as_float(((unsigned)(thrbin_s << 3)) << 16) - 0.1f;  // covers 2E

    // ordered candidate collection (ascending index), cap CAP
    if (tid == 0) base_s = 0;
    __syncthreads();
    for (int c0 = 0; c0 < LI; c0 += 256) {
        float kf = __uint_as_float(((unsigned)z[c0 + tid]) << 16);
        bool f = kf >= bandlo;
        unsigned long long m = __ballot(f);
        if (lane == 0) red[w] = __popcll(m);
        __syncthreads();
        int wbase = base_s;
        for (int ww = 0; ww < w; ++ww) wbase += red[ww];
        int pos = wbase + __popcll(m & ((1ull << lane) - 1ull));
        if (f && pos < CAP) {
            band[row * CAP + pos] = c0 + tid;
            atomicAdd(&ghist[c0 + tid], 1);
        }
        __syncthreads();
        if (tid == 0) base_s += red[0] + red[1] + red[2] + red[3];
        __syncthreads();
    }
    if (tid == 0) bandcnt[row] = base_s < CAP ? base_s : CAP;
}

// ---- exclusive prefix-sum of ghist[8192] -> offs, cursor (single block)
__global__ __launch_bounds__(256) void k_scan(
    const int* __restrict__ ghist, int* __restrict__ offs, int* __restrict__ cursor)
{
    __shared__ int sums[256];
    const int tid = threadIdx.x;
    int loc[32];
    int s = 0;
    #pragma unroll
    for (int b = 0; b < 32; ++b) { loc[b] = s; s += ghist[tid * 32 + b]; }
    sums[tid] = s;
    __syncthreads();
    for (int st = 1; st < 256; st <<= 1) {
        int v = (tid >= st) ? sums[tid - st] : 0;
        __syncthreads();
        sums[tid] += v;
        __syncthreads();
    }
    int base = (tid > 0) ? sums[tid - 1] : 0;
    #pragma unroll
    for (int b = 0; b < 32; ++b) {
        int o = base + loc[b];
        offs[tid * 32 + b]   = o;
        cursor[tid * 32 + b] = o;
    }
}

// ---- scatter band entries into neuron-major inverted list
__global__ __launch_bounds__(256) void k_scatter(
    const int* __restrict__ band, const int* __restrict__ bandcnt,
    int* __restrict__ cursor, int* __restrict__ inv)
{
    const int row = blockIdx.x;
    const int tid = threadIdx.x;
    int cnt = bandcnt[row];
    if (tid < cnt) {
        int j = band[row * CAP + tid] & (LI - 1);
        int p = atomicAdd(&cursor[j], 1);
        inv[p] = (row << 8) | tid;
    }
}

// ---- neuron-major exact rescore: stream gate[j],up[j] once (fp32), gather x
__global__ __launch_bounds__(256) void k_pair(
    const float* __restrict__ x, const float* __restrict__ gate,
    const float* __restrict__ up, const int* __restrict__ layer_idx,
    const int* __restrict__ ghist, const int* __restrict__ offs,
    const int* __restrict__ inv,
    float* __restrict__ gdot, float* __restrict__ udot)
{
    __shared__ float gs[LD];   // 8 KB
    __shared__ float us[LD];   // 8 KB
    const int j = blockIdx.x;
    const int tid = threadIdx.x;
    const int lane = tid & 63, w = tid >> 6;
    const int nj = ghist[j];
    if (nj == 0) return;
    const float* __restrict__ gr = gate + (size_t)layer_idx[0] * LI * LD + (size_t)j * LD;
    const float* __restrict__ ur = up   + (size_t)layer_idx[0] * LI * LD + (size_t)j * LD;
    for (int i = tid * 4; i < LD; i += 1024) {
        *(float4*)&gs[i] = *(const float4*)(gr + i);
        *(float4*)&us[i] = *(const float4*)(ur + i);
    }
    __syncthreads();
    const int base = offs[j];
    for (int e = w; e < nj; e += 4) {
        int packed = inv[base + e];
        int row = packed >> 8, slot = packed & 255;
        const float* __restrict__ xr = x + (size_t)row * LD;
        float gd = 0.f, ud = 0.f;
        for (int i = lane * 4; i < LD; i += 256) {
            float4 xv = *(const float4*)(xr + i);
            gd = fmaf(xv.x, gs[i+0], gd); gd = fmaf(xv.y, gs[i+1], gd);
            gd = fmaf(xv.z, gs[i+2], gd); gd = fmaf(xv.w, gs[i+3], gd);
            ud = fmaf(xv.x, us[i+0], ud); ud = fmaf(xv.y, us[i+1], ud);
            ud = fmaf(xv.z, us[i+2], ud); ud = fmaf(xv.w, us[i+3], ud);
        }
        #pragma unroll
        for (int o = 32; o; o >>= 1) {
            gd += __shfl_down(gd, o);
            ud += __shfl_down(ud, o);
        }
        if (lane == 0) {
            gdot[(size_t)row * CAP + slot] = gd;
            udot[(size_t)row * CAP + slot] = ud;
        }
    }
}

// ---- per-row exact top-32 among band (desc exact key, asc idx); gu = silu*u
__global__ __launch_bounds__(256) void k_final(
    const int* __restrict__ band, const int* __restrict__ bandcnt,
    const float* __restrict__ gdot, const float* __restrict__ udot,
    int* __restrict__ idx_out, float* __restrict__ gu_out)
{
    __shared__ float ckey[CAP];
    __shared__ float cgu[CAP];
    __shared__ int   cidx[CAP];
    const int row = blockIdx.x;
    const int tid = threadIdx.x;
    const int lane = tid & 63;
    const int cnt = bandcnt[row];
    if (tid < CAP) { ckey[tid] = -1.f; cgu[tid] = 0.f; cidx[tid] = 0x7fffffff; }
    __syncthreads();
    if (tid < cnt) {
        float gd = gdot[(size_t)row * CAP + tid];
        float g = gd / (1.f + expf(-gd));
        ckey[tid] = fabsf(g);
        cgu[tid]  = g * udot[(size_t)row * CAP + tid];
        cidx[tid] = band[row * CAP + tid];
    }
    __syncthreads();
    if (tid < 64) {
        float k1 = ckey[lane], k2 = ckey[lane + 64], k3 = ckey[lane + 128];
        int   i1 = cidx[lane], i2 = cidx[lane + 64], i3 = cidx[lane + 128];
        int   p1 = lane, p2 = lane + 64, p3 = lane + 128;
        for (int slot = 0; slot < LK; ++slot) {
            float bk = k1; int bi_ = i1, bp = p1;
            if (k2 > bk || (k2 == bk && i2 < bi_)) { bk = k2; bi_ = i2; bp = p2; }
            if (k3 > bk || (k3 == bk && i3 < bi_)) { bk = k3; bi_ = i3; bp = p3; }
            #pragma unroll
            for (int o = 1; o < 64; o <<= 1) {
                float ok = __shfl_xor(bk, o);
                int  oi = __shfl_xor(bi_, o);
                int  op = __shfl_xor(bp, o);
                if (ok > bk || (ok == bk && oi < bi_)) { bk = ok; bi_ = oi; bp = op; }
            }
            if (lane == 0) {
                idx_out[row * LK + slot] = bi_ & (LI - 1);
                gu_out[row * LK + slot]  = cgu[bp < CAP ? bp : 0];
            }
            if (p1 == bp) { k1 = -1.f; i1 = 0x7fffffff; }
            if (p2 == bp) { k2 = -1.f; i2 = 0x7fffffff; }
            if (p3 == bp) { k3 = -1.f; i3 = 0x7fffffff; }
        }
    }
}

// ---- transpose down[D,I] -> dT[I,D]
__global__ __launch_bounds__(256) void k_transpose(
    const float* __restrict__ down, const int* __restrict__ layer_idx,
    float* __restrict__ dT)
{
    const float* __restrict__ dw = down + (size_t)layer_idx[0] * LD * LI;
    __shared__ float t[32][33];
    const int bi = blockIdx.x * 32;
    const int bd = blockIdx.y * 32;
    const int tx = threadIdx.x & 31, ty = threadIdx.x >> 5;
    #pragma unroll
    for (int r = ty; r < 32; r += 8)
        t[r][tx] = dw[(size_t)(bd + r) * LI + bi + tx];
    __syncthreads();
    #pragma unroll
    for (int r = ty; r < 32; r += 8)
        dT[(size_t)(bi + r) * LD + bd + tx] = t[tx][r];
}

// ---- out[n,:] = sum_k gu[n,k] * dT[idx[n,k], :]
__global__ __launch_bounds__(256) void k_down(
    const float* __restrict__ dT, const int* __restrict__ idx,
    const float* __restrict__ gu, float* __restrict__ out)
{
    __shared__ int   js[LK];
    __shared__ float wgt[LK];
    const int row = blockIdx.x;
    const int tid = threadIdx.x;
    if (tid < LK) {
        js[tid]  = idx[row * LK + tid] & (LI - 1);
        wgt[tid] = gu[row * LK + tid];
    }
    __syncthreads();
    float4 a0 = {0.f,0.f,0.f,0.f}, a1 = {0.f,0.f,0.f,0.f};
    #pragma unroll 4
    for (int k = 0; k < LK; ++k) {
        const float* __restrict__ dr = dT + (size_t)js[k] * LD;
        float wv = wgt[k];
        float4 v0 = *(const float4*)(dr + tid * 4);
        float4 v1 = *(const float4*)(dr + 1024 + tid * 4);
        a0.x = fmaf(wv, v0.x, a0.x); a0.y = fmaf(wv, v0.y, a0.y);
        a0.z = fmaf(wv, v0.z, a0.z); a0.w = fmaf(wv, v0.w, a0.w);
        a1.x = fmaf(wv, v1.x, a1.x); a1.y = fmaf(wv, v1.y, a1.y);
        a1.z = fmaf(wv, v1.z, a1.z); a1.w = fmaf(wv, v1.w, a1.w);
    }
    float* o = out + (size_t)row * LD;
    *(float4*)(o + tid * 4) = a0;
    *(float4*)(o + 1024 + tid * 4) = a1;
}

extern "C" void kernel_launch(void* const* d_in, const int* in_sizes, int n_in,
                              void* d_out, int out_size, void* d_ws, size_t ws_size,
                              hipStream_t stream)
{
    const float* x      = (const float*)d_in[0];
    const float* gate   = (const float*)d_in[1];
    const float* up     = (const float*)d_in[2];
    const float* down   = (const float*)d_in[3];
    const int* layer_idx = (const int*)d_in[4];
    float* out = (float*)d_out;

    // ---- ws layout: small region, then big region (xh|wh|zk, reused for dT)
    const size_t NK = (size_t)LN * LK;
    const size_t NC_ = (size_t)LN * CAP;
    char* p = (char*)d_ws;
    int*   idx     = (int*)p;            p += NK * 4;
    float* gu      = (float*)p;          p += NK * 4;
    int*   band    = (int*)p;            p += NC_ * 4;
    int*   bandcnt = (int*)p;            p += (size_t)LN * 4;
    int*   ghist   = (int*)p;            p += (size_t)LI * 4;
    int*   offs    = (int*)p;            p += (size_t)LI * 4;
    int*   cursor  = (int*)p;            p += (size_t)LI * 4;
    int*   inv     = (int*)p;            p += NC_ * 4;
    float* gdot    = (float*)p;          p += NC_ * 4;
    float* udot    = (float*)p;          p += NC_ * 4;
    p = (char*)(((size_t)p + 255) & ~(size_t)255);

    const size_t xcnt = (size_t)LN * LD;
    const size_t wcnt = (size_t)LI * LD;
    unsigned short* xh = (unsigned short*)p;
    unsigned short* wh = xh + xcnt;
    unsigned short* zk = wh + wcnt;
    char* big_end = (char*)(zk + (size_t)LN * LI);
    float* dT = (float*)p;   // overlays xh|wh|zk after k_select (64 MB <= 72 MB)

    if ((size_t)(big_end - (char*)d_ws) > ws_size) return;   // ws too small

    k_cvt_h<<<512,  256, 0, stream>>>(x,    layer_idx, 0,    xh, (int)(xcnt / 4));
    k_cvt_h<<<2048, 256, 0, stream>>>(gate, layer_idx, wcnt, wh, (int)(wcnt / 4));
    k_gemm_z<<<dim3(LI / 128, LN / 128), 256, 0, stream>>>(xh, wh, zk);

    hipMemsetAsync(ghist, 0, (size_t)LI * 4, stream);
    k_select<<<LN, 256, 0, stream>>>(zk, band, bandcnt, ghist);
    k_scan<<<1, 256, 0, stream>>>(ghist, offs, cursor);
    k_scatter<<<LN, 256, 0, stream>>>(band, bandcnt, cursor, inv);
    k_pair<<<LI, 256, 0, stream>>>(x, gate, up, layer_idx, ghist, offs, inv, gdot, udot);
    k_final<<<LN, 256, 0, stream>>>(band, bandcnt, gdot, udot, idx, gu);

    k_transpose<<<dim3(LI / 32, LD / 32), 256, 0, stream>>>(down, layer_idx, dT);
    k_down<<<LN, 256, 0, stream>>>(dT, idx, gu, out);
}

// Round 6
// 432.151 us; speedup vs baseline: 2.4705x; 1.0024x over previous
//
#include <hip/hip_runtime.h>
#include <math.h>

constexpr int LI = 8192;   // I (intermediate)
constexpr int LD = 2048;   // D (hidden)
constexpr int LN = 2048;   // N (tokens)
constexpr int LK = 32;     // top_k
constexpr int CAP = 192;   // candidate band cap per row

typedef short short8 __attribute__((ext_vector_type(8)));
typedef float f32x4 __attribute__((ext_vector_type(4)));
typedef const __attribute__((address_space(1))) void* gas1_t;
typedef __attribute__((address_space(3))) void* las3_t;

__device__ __forceinline__ void gload16(const void* g, void* l) {
    __builtin_amdgcn_global_load_lds((gas1_t)g, (las3_t)l, 16, 0, 0);
}

// ---- fp32 -> bf16 (RNE), layer-indirected source
__global__ __launch_bounds__(256) void k_cvt_h(
    const float* __restrict__ src, const int* __restrict__ layer_idx,
    size_t lstride, unsigned short* __restrict__ hi, int n4)
{
    const float* __restrict__ s = src + (size_t)layer_idx[0] * lstride;
    int i = blockIdx.x * 256 + threadIdx.x;
    int stride = gridDim.x * 256;
    for (; i < n4; i += stride) {
        float4 v = ((const float4*)s)[i];
        float f[4] = {v.x, v.y, v.z, v.w};
        unsigned short hh[4];
        #pragma unroll
        for (int j = 0; j < 4; ++j) {
            unsigned u = __float_as_uint(f[j]);
            hh[j] = (unsigned short)((u + 0x7fffu + ((u >> 16) & 1u)) >> 16);
        }
        ushort4 h = {hh[0], hh[1], hh[2], hh[3]};
        ((ushort4*)hi)[i] = h;
    }
}

// ---- zk = bf16(|silu(x @ gw^T)|) via single bf16 MFMA, 128x128 tile, BK=64.
// Structure verified in round 4 (passed); lo-terms removed, key epilogue added.
__global__ __launch_bounds__(256) void k_gemm_z(
    const unsigned short* __restrict__ xh, const unsigned short* __restrict__ wh,
    unsigned short* __restrict__ zk)
{
    __shared__ short lds[16384];   // Ah|Bh, each [128][64] bf16 = 16KB
    short* Ah = lds;
    short* Bh = lds + 8192;

    const int tid = threadIdx.x;
    const int w = tid >> 6, lane = tid & 63;
    const int bn = blockIdx.y * 128;   // token rows
    const int bi = blockIdx.x * 128;   // neuron rows

    const int srow   = w * 32 + (lane >> 3);
    const int schunk = (lane & 7) ^ ((lane >> 3) & 7);   // inverse-swizzled source
    const unsigned short* xbh = xh + (size_t)(bn + srow) * LD + schunk * 8;
    const unsigned short* wbh = wh + (size_t)(bi + srow) * LD + schunk * 8;

    f32x4 acc[4][4];
    #pragma unroll
    for (int m = 0; m < 4; ++m)
        #pragma unroll
        for (int n = 0; n < 4; ++n) acc[m][n] = (f32x4){0.f, 0.f, 0.f, 0.f};

    const int wm = (w >> 1) * 64, wn = (w & 1) * 64;

    #define STAGE(k0)                                                          \
        {                                                                      \
            _Pragma("unroll")                                                  \
            for (int t = 0; t < 4; ++t) {                                      \
                int ldo = (w * 32 + t * 8) * 64;                               \
                size_t go = (size_t)t * 8 * LD + (k0);                         \
                gload16(xbh + go, Ah + ldo);                                   \
                gload16(wbh + go, Bh + ldo);                                   \
            }                                                                  \
        }

    STAGE(0);
    __syncthreads();
    for (int k0 = 0;;) {
        #pragma unroll
        for (int ks = 0; ks < 2; ++ks) {
            short8 a_h[4], b_h[4];
            #pragma unroll
            for (int m = 0; m < 4; ++m) {
                int lr = wm + m * 16 + (lane & 15);
                int lc = ks * 4 + (lane >> 4);
                a_h[m] = *(const short8*)(Ah + lr * 64 + ((lc ^ (lr & 7)) << 3));
            }
            #pragma unroll
            for (int n = 0; n < 4; ++n) {
                int lr = wn + n * 16 + (lane & 15);
                int lc = ks * 4 + (lane >> 4);
                b_h[n] = *(const short8*)(Bh + lr * 64 + ((lc ^ (lr & 7)) << 3));
            }
            #pragma unroll
            for (int m = 0; m < 4; ++m)
                #pragma unroll
                for (int n = 0; n < 4; ++n)
                    acc[m][n] = __builtin_amdgcn_mfma_f32_16x16x32_bf16(a_h[m], b_h[n], acc[m][n], 0, 0, 0);
        }
        k0 += 64;
        if (k0 >= LD) break;
        __syncthreads();
        STAGE(k0);
        __syncthreads();
    }

    // epilogue: key = bf16(|silu(z)|); C/D layout col=lane&15, row=(lane>>4)*4+r
    #pragma unroll
    for (int m = 0; m < 4; ++m) {
        int rb = bn + wm + m * 16 + (lane >> 4) * 4;
        #pragma unroll
        for (int n = 0; n < 4; ++n) {
            int cb = bi + wn + n * 16 + (lane & 15);
            #pragma unroll
            for (int r = 0; r < 4; ++r) {
                float zv = acc[m][n][r];
                float g = zv / (1.f + expf(-zv));
                unsigned u = __float_as_uint(fabsf(g));
                zk[(size_t)(rb + r) * LI + cb] =
                    (unsigned short)((u + 0x7fffu + ((u >> 16) & 1u)) >> 16);
            }
        }
    }
    #undef STAGE
}

// ---- per-row band selection: 4096-bin histogram on bf16 key bits, threshold
// bin covering rank-32, collect keys >= binfloor - MARGIN (superset of top-32).
__global__ __launch_bounds__(256) void k_select(
    const unsigned short* __restrict__ zk, int* __restrict__ band,
    int* __restrict__ bandcnt, int* __restrict__ ghist)
{
    __shared__ int hist[4096];   // 16 KB
    __shared__ int sums[256];
    __shared__ int red[4];
    __shared__ int base_s;
    __shared__ int thrbin_s;

    const int row = blockIdx.x;
    const int tid = threadIdx.x;
    const int lane = tid & 63, w = tid >> 6;
    const unsigned short* __restrict__ z = zk + (size_t)row * LI;

    if (tid == 0) thrbin_s = 0;
    for (int i = tid; i < 4096; i += 256) hist[i] = 0;
    __syncthreads();
    for (int i = tid; i < LI; i += 256)
        atomicAdd(&hist[z[i] >> 3], 1);   // sign=0: uint order == value order
    __syncthreads();

    int own = 0;
    #pragma unroll
    for (int b = 0; b < 16; ++b) own += hist[tid * 16 + b];
    sums[tid] = own;
    __syncthreads();
    // suffix inclusive scan: sums[t] = sum_{u>=t} own_u
    for (int st = 1; st < 256; st <<= 1) {
        int v = (tid + st < 256) ? sums[tid + st] : 0;
        __syncthreads();
        sums[tid] += v;
        __syncthreads();
    }
    int after = (tid < 255) ? sums[tid + 1] : 0;   // strictly above my 16 bins
    if (after < LK && after + own >= LK) {          // unique crossing thread
        int cum = after;
        for (int b = 15; b >= 0; --b) {
            cum += hist[tid * 16 + b];
            if (cum >= LK) { thrbin_s = tid * 16 + b; break; }
        }
    }
    __syncthreads();
    const float bandlo =
        __uint_as_float(((unsigned)(thrbin_s << 3)) << 16) - 0.1f;  // covers 2E

    // ordered candidate collection (ascending index), cap CAP
    if (tid == 0) base_s = 0;
    __syncthreads();
    for (int c0 = 0; c0 < LI; c0 += 256) {
        float kf = __uint_as_float(((unsigned)z[c0 + tid]) << 16);
        bool f = kf >= bandlo;
        unsigned long long m = __ballot(f);
        if (lane == 0) red[w] = __popcll(m);
        __syncthreads();
        int wbase = base_s;
        for (int ww = 0; ww < w; ++ww) wbase += red[ww];
        int pos = wbase + __popcll(m & ((1ull << lane) - 1ull));
        if (f && pos < CAP) {
            band[row * CAP + pos] = c0 + tid;
            atomicAdd(&ghist[c0 + tid], 1);
        }
        __syncthreads();
        if (tid == 0) base_s += red[0] + red[1] + red[2] + red[3];
        __syncthreads();
    }
    if (tid == 0) bandcnt[row] = base_s < CAP ? base_s : CAP;
}

// ---- exclusive prefix-sum of ghist[8192] -> offs, cursor (single block)
__global__ __launch_bounds__(256) void k_scan(
    const int* __restrict__ ghist, int* __restrict__ offs, int* __restrict__ cursor)
{
    __shared__ int sums[256];
    const int tid = threadIdx.x;
    int loc[32];
    int s = 0;
    #pragma unroll
    for (int b = 0; b < 32; ++b) { loc[b] = s; s += ghist[tid * 32 + b]; }
    sums[tid] = s;
    __syncthreads();
    for (int st = 1; st < 256; st <<= 1) {
        int v = (tid >= st) ? sums[tid - st] : 0;
        __syncthreads();
        sums[tid] += v;
        __syncthreads();
    }
    int base = (tid > 0) ? sums[tid - 1] : 0;
    #pragma unroll
    for (int b = 0; b < 32; ++b) {
        int o = base + loc[b];
        offs[tid * 32 + b]   = o;
        cursor[tid * 32 + b] = o;
    }
}

// ---- scatter band entries into neuron-major inverted list
__global__ __launch_bounds__(256) void k_scatter(
    const int* __restrict__ band, const int* __restrict__ bandcnt,
    int* __restrict__ cursor, int* __restrict__ inv)
{
    const int row = blockIdx.x;
    const int tid = threadIdx.x;
    int cnt = bandcnt[row];
    if (tid < cnt) {
        int j = band[row * CAP + tid] & (LI - 1);
        int p = atomicAdd(&cursor[j], 1);
        inv[p] = (row << 8) | tid;
    }
}

// ---- neuron-major exact rescore: stream gate[j],up[j] once (fp32), gather x
__global__ __launch_bounds__(256) void k_pair(
    const float* __restrict__ x, const float* __restrict__ gate,
    const float* __restrict__ up, const int* __restrict__ layer_idx,
    const int* __restrict__ ghist, const int* __restrict__ offs,
    const int* __restrict__ inv,
    float* __restrict__ gdot, float* __restrict__ udot)
{
    __shared__ float gs[LD];   // 8 KB
    __shared__ float us[LD];   // 8 KB
    const int j = blockIdx.x;
    const int tid = threadIdx.x;
    const int lane = tid & 63, w = tid >> 6;
    const int nj = ghist[j];
    if (nj == 0) return;
    const float* __restrict__ gr = gate + (size_t)layer_idx[0] * LI * LD + (size_t)j * LD;
    const float* __restrict__ ur = up   + (size_t)layer_idx[0] * LI * LD + (size_t)j * LD;
    for (int i = tid * 4; i < LD; i += 1024) {
        *(float4*)&gs[i] = *(const float4*)(gr + i);
        *(float4*)&us[i] = *(const float4*)(ur + i);
    }
    __syncthreads();
    const int base = offs[j];
    for (int e = w; e < nj; e += 4) {
        int packed = inv[base + e];
        int row = packed >> 8, slot = packed & 255;
        const float* __restrict__ xr = x + (size_t)row * LD;
        float gd = 0.f, ud = 0.f;
        for (int i = lane * 4; i < LD; i += 256) {
            float4 xv = *(const float4*)(xr + i);
            gd = fmaf(xv.x, gs[i+0], gd); gd = fmaf(xv.y, gs[i+1], gd);
            gd = fmaf(xv.z, gs[i+2], gd); gd = fmaf(xv.w, gs[i+3], gd);
            ud = fmaf(xv.x, us[i+0], ud); ud = fmaf(xv.y, us[i+1], ud);
            ud = fmaf(xv.z, us[i+2], ud); ud = fmaf(xv.w, us[i+3], ud);
        }
        #pragma unroll
        for (int o = 32; o; o >>= 1) {
            gd += __shfl_down(gd, o);
            ud += __shfl_down(ud, o);
        }
        if (lane == 0) {
            gdot[(size_t)row * CAP + slot] = gd;
            udot[(size_t)row * CAP + slot] = ud;
        }
    }
}

// ---- per-row exact top-32 among band (desc exact key, asc idx); gu = silu*u
__global__ __launch_bounds__(256) void k_final(
    const int* __restrict__ band, const int* __restrict__ bandcnt,
    const float* __restrict__ gdot, const float* __restrict__ udot,
    int* __restrict__ idx_out, float* __restrict__ gu_out)
{
    __shared__ float ckey[CAP];
    __shared__ float cgu[CAP];
    __shared__ int   cidx[CAP];
    const int row = blockIdx.x;
    const int tid = threadIdx.x;
    const int lane = tid & 63;
    const int cnt = bandcnt[row];
    if (tid < CAP) { ckey[tid] = -1.f; cgu[tid] = 0.f; cidx[tid] = 0x7fffffff; }
    __syncthreads();
    if (tid < cnt) {
        float gd = gdot[(size_t)row * CAP + tid];
        float g = gd / (1.f + expf(-gd));
        ckey[tid] = fabsf(g);
        cgu[tid]  = g * udot[(size_t)row * CAP + tid];
        cidx[tid] = band[row * CAP + tid];
    }
    __syncthreads();
    if (tid < 64) {
        float k1 = ckey[lane], k2 = ckey[lane + 64], k3 = ckey[lane + 128];
        int   i1 = cidx[lane], i2 = cidx[lane + 64], i3 = cidx[lane + 128];
        int   p1 = lane, p2 = lane + 64, p3 = lane + 128;
        for (int slot = 0; slot < LK; ++slot) {
            float bk = k1; int bi_ = i1, bp = p1;
            if (k2 > bk || (k2 == bk && i2 < bi_)) { bk = k2; bi_ = i2; bp = p2; }
            if (k3 > bk || (k3 == bk && i3 < bi_)) { bk = k3; bi_ = i3; bp = p3; }
            #pragma unroll
            for (int o = 1; o < 64; o <<= 1) {
                float ok = __shfl_xor(bk, o);
                int  oi = __shfl_xor(bi_, o);
                int  op = __shfl_xor(bp, o);
                if (ok > bk || (ok == bk && oi < bi_)) { bk = ok; bi_ = oi; bp = op; }
            }
            if (lane == 0) {
                idx_out[row * LK + slot] = bi_ & (LI - 1);
                gu_out[row * LK + slot]  = cgu[bp < CAP ? bp : 0];
            }
            if (p1 == bp) { k1 = -1.f; i1 = 0x7fffffff; }
            if (p2 == bp) { k2 = -1.f; i2 = 0x7fffffff; }
            if (p3 == bp) { k3 = -1.f; i3 = 0x7fffffff; }
        }
    }
}

// ---- transpose down[D,I] -> dT[I,D]
__global__ __launch_bounds__(256) void k_transpose(
    const float* __restrict__ down, const int* __restrict__ layer_idx,
    float* __restrict__ dT)
{
    const float* __restrict__ dw = down + (size_t)layer_idx[0] * LD * LI;
    __shared__ float t[32][33];
    const int bi = blockIdx.x * 32;
    const int bd = blockIdx.y * 32;
    const int tx = threadIdx.x & 31, ty = threadIdx.x >> 5;
    #pragma unroll
    for (int r = ty; r < 32; r += 8)
        t[r][tx] = dw[(size_t)(bd + r) * LI + bi + tx];
    __syncthreads();
    #pragma unroll
    for (int r = ty; r < 32; r += 8)
        dT[(size_t)(bi + r) * LD + bd + tx] = t[tx][r];
}

// ---- out[n,:] = sum_k gu[n,k] * dT[idx[n,k], :]
__global__ __launch_bounds__(256) void k_down(
    const float* __restrict__ dT, const int* __restrict__ idx,
    const float* __restrict__ gu, float* __restrict__ out)
{
    __shared__ int   js[LK];
    __shared__ float wgt[LK];
    const int row = blockIdx.x;
    const int tid = threadIdx.x;
    if (tid < LK) {
        js[tid]  = idx[row * LK + tid] & (LI - 1);
        wgt[tid] = gu[row * LK + tid];
    }
    __syncthreads();
    float4 a0 = {0.f,0.f,0.f,0.f}, a1 = {0.f,0.f,0.f,0.f};
    #pragma unroll 4
    for (int k = 0; k < LK; ++k) {
        const float* __restrict__ dr = dT + (size_t)js[k] * LD;
        float wv = wgt[k];
        float4 v0 = *(const float4*)(dr + tid * 4);
        float4 v1 = *(const float4*)(dr + 1024 + tid * 4);
        a0.x = fmaf(wv, v0.x, a0.x); a0.y = fmaf(wv, v0.y, a0.y);
        a0.z = fmaf(wv, v0.z, a0.z); a0.w = fmaf(wv, v0.w, a0.w);
        a1.x = fmaf(wv, v1.x, a1.x); a1.y = fmaf(wv, v1.y, a1.y);
        a1.z = fmaf(wv, v1.z, a1.z); a1.w = fmaf(wv, v1.w, a1.w);
    }
    float* o = out + (size_t)row * LD;
    *(float4*)(o + tid * 4) = a0;
    *(float4*)(o + 1024 + tid * 4) = a1;
}

extern "C" void kernel_launch(void* const* d_in, const int* in_sizes, int n_in,
                              void* d_out, int out_size, void* d_ws, size_t ws_size,
                              hipStream_t stream)
{
    const float* x      = (const float*)d_in[0];
    const float* gate   = (const float*)d_in[1];
    const float* up     = (const float*)d_in[2];
    const float* down   = (const float*)d_in[3];
    const int* layer_idx = (const int*)d_in[4];
    float* out = (float*)d_out;

    // ---- ws layout: small region, then big region (xh|wh|zk, reused for dT)
    const size_t NK = (size_t)LN * LK;
    const size_t NC_ = (size_t)LN * CAP;
    char* p = (char*)d_ws;
    int*   idx     = (int*)p;            p += NK * 4;
    float* gu      = (float*)p;          p += NK * 4;
    int*   band    = (int*)p;            p += NC_ * 4;
    int*   bandcnt = (int*)p;            p += (size_t)LN * 4;
    int*   ghist   = (int*)p;            p += (size_t)LI * 4;
    int*   offs    = (int*)p;            p += (size_t)LI * 4;
    int*   cursor  = (int*)p;            p += (size_t)LI * 4;
    int*   inv     = (int*)p;            p += NC_ * 4;
    float* gdot    = (float*)p;          p += NC_ * 4;
    float* udot    = (float*)p;          p += NC_ * 4;
    p = (char*)(((size_t)p + 255) & ~(size_t)255);

    const size_t xcnt = (size_t)LN * LD;
    const size_t wcnt = (size_t)LI * LD;
    unsigned short* xh = (unsigned short*)p;
    unsigned short* wh = xh + xcnt;
    unsigned short* zk = wh + wcnt;
    char* big_end = (char*)(zk + (size_t)LN * LI);
    float* dT = (float*)p;   // overlays xh|wh|zk after k_select (64 MB <= 72 MB)

    if ((size_t)(big_end - (char*)d_ws) > ws_size) return;   // ws too small

    k_cvt_h<<<512,  256, 0, stream>>>(x,    layer_idx, 0,    xh, (int)(xcnt / 4));
    k_cvt_h<<<2048, 256, 0, stream>>>(gate, layer_idx, wcnt, wh, (int)(wcnt / 4));
    k_gemm_z<<<dim3(LI / 128, LN / 128), 256, 0, stream>>>(xh, wh, zk);

    hipMemsetAsync(ghist, 0, (size_t)LI * 4, stream);
    k_select<<<LN, 256, 0, stream>>>(zk, band, bandcnt, ghist);
    k_scan<<<1, 256, 0, stream>>>(ghist, offs, cursor);
    k_scatter<<<LN, 256, 0, stream>>>(band, bandcnt, cursor, inv);
    k_pair<<<LI, 256, 0, stream>>>(x, gate, up, layer_idx, ghist, offs, inv, gdot, udot);
    k_final<<<LN, 256, 0, stream>>>(band, bandcnt, gdot, udot, idx, gu);

    k_transpose<<<dim3(LI / 32, LD / 32), 256, 0, stream>>>(down, layer_idx, dT);
    k_down<<<LN, 256, 0, stream>>>(dT, idx, gu, out);
}